// Round 13
// baseline (334.835 us; speedup 1.0000x reference)
//
#include <hip/hip_runtime.h>
#include <hip/hip_bf16.h>

// LPKT forward. B=128, S=128, C=128, D=64.
//  - pre1/pre2: parallel precompute, 16 positions/block (4x fewer weight
//    re-reads). Outputs pre-scaled by -log2e (pre2 by -2log2e) for exp2
//    sigmoids.
//  - lpkt_seq: one 512-thread block per batch, 127-step recurrence, TWO
//    barriers per step. h in registers (8 waves x 32c x 32d), bf16 shadow in
//    LDS for MFMA (acc = pre4 + h@W4a' + LG@W4b' [broadcast-B]). Serial chain
//    (a2,a3,LG) on w4 only, f16-packed register weights + v_dot2_f32_f16.
//    ALL bf16 packs via hardware v_cvt_pk_bf16_f32 (inline asm).
//    y head on w6; ring refills on w3 (q rows) / w7 (pre streams).

#define NB 128
#define NS 128
#define NC 128
#define ND 64
#define POS (NB*NS)

typedef __attribute__((ext_vector_type(8))) short short8;
typedef __attribute__((ext_vector_type(4))) float f32x4;
typedef __attribute__((ext_vector_type(2))) _Float16 half2_t;

__device__ __forceinline__ float rl(float v,int j){
  return __int_as_float(__builtin_amdgcn_readlane(__float_as_int(v), j));
}
__device__ __forceinline__ half2_t rlh2(half2_t v,int j){
  int x; __builtin_memcpy(&x,&v,4);
  x = __builtin_amdgcn_readlane(x,j);
  half2_t r; __builtin_memcpy(&r,&x,4); return r;
}
__device__ __forceinline__ half2_t pkrtz(float a, float b){
  auto t = __builtin_amdgcn_cvt_pkrtz(a,b);
  half2_t r; __builtin_memcpy(&r,&t,4); return r;
}
__device__ __forceinline__ unsigned pk_bf16(float lo, float hi){  // HW cvt_pk
  unsigned r;
  asm("v_cvt_pk_bf16_f32 %0, %1, %2" : "=v"(r) : "v"(lo), "v"(hi));
  return r;
}
__device__ __forceinline__ float dppswap(float v){  // lane 2k <-> 2k+1
  return __int_as_float(__builtin_amdgcn_update_dpp(0,__float_as_int(v),0xB1,0xF,0xF,true));
}
__device__ __forceinline__ float dot2h(half2_t a, half2_t b, float c){
#if __has_builtin(__builtin_amdgcn_fdot2)
  return __builtin_amdgcn_fdot2(a,b,c,false);
#else
  return fmaf((float)a[0],(float)b[0], fmaf((float)a[1],(float)b[1], c));
#endif
}

#define HBF(c, d) ((((c)<<6) + (d)) ^ (((c)&7)<<3))
#define DPP_ADD(v, CTRL) ((v) + __int_as_float(__builtin_amdgcn_update_dpp(0, __float_as_int(v), CTRL, 0xF, 0xF, true)))
#define DPP_ROWSUM(v) do { v = DPP_ADD(v,0x111); v = DPP_ADD(v,0x112); v = DPP_ADD(v,0x114); v = DPP_ADD(v,0x118); } while(0)

#define SC1 (-1.4426950408889634f)   /* -log2(e) */

__device__ __forceinline__ float gsig(float zp){   // sigmoid given pre-scaled arg
  return __builtin_amdgcn_rcpf(1.f + __builtin_amdgcn_exp2f(zp));
}

// ---------------- P1: AL = [e,at,c]@W1+b1 ; pre4=(it@W4c+b4)*SC1 ; pre5=(e@W5a+b5)*SC1
// 16 positions per 64-thread block; 1024 blocks.
__global__ __launch_bounds__(64) void lpkt_pre1(
    const int* __restrict__ qseq, const int* __restrict__ cseq,
    const int* __restrict__ itseq, const int* __restrict__ atseq,
    const float* __restrict__ E_q, const float* __restrict__ E_c,
    const float* __restrict__ E_it, const float* __restrict__ E_at,
    const float* __restrict__ W1, const float* __restrict__ b1,
    const float* __restrict__ W4, const float* __restrict__ b4,
    const float* __restrict__ W5, const float* __restrict__ b5,
    float* __restrict__ AL, float* __restrict__ pre4, float* __restrict__ pre5)
{
  __shared__ float sx[16][192];
  __shared__ float sit[16][64];
  const int d = threadIdx.x;
  const int base = blockIdx.x * 16;
  #pragma unroll 4
  for (int i = 0; i < 16; ++i) {
    int p = base + i;
    sx[i][d]      = E_q[qseq[p]*ND + d];
    sx[i][64+d]   = E_at[atseq[p]*ND + d];
    sx[i][128+d]  = E_c[cseq[p]*ND + d];
    sit[i][d]     = E_it[itseq[p]*ND + d];
  }
  __syncthreads();
  float al[16], p4[16], p5[16];
  const float b1d = b1[d], b4d = b4[d], b5d = b5[d];
  #pragma unroll
  for (int i = 0; i < 16; ++i) { al[i] = b1d; p4[i] = b4d; p5[i] = b5d; }
  for (int k = 0; k < 192; ++k) {
    float wv = W1[k*ND + d];
    #pragma unroll
    for (int i = 0; i < 16; ++i) al[i] = fmaf(sx[i][k], wv, al[i]);
  }
  for (int k = 0; k < 64; ++k) {
    float wv4 = W4[(128+k)*ND + d];
    float wv5 = W5[k*ND + d];
    #pragma unroll
    for (int i = 0; i < 16; ++i) {
      p4[i] = fmaf(sit[i][k], wv4, p4[i]);
      p5[i] = fmaf(sx[i][k],  wv5, p5[i]);
    }
  }
  #pragma unroll
  for (int i = 0; i < 16; ++i) {
    int p = base + i;
    AL[p*ND + d]   = al[i];
    pre4[p*ND + d] = p4[i]*SC1;
    pre5[p*ND + d] = p5[i]*SC1;
  }
}

// ---------------- P2: pre2/pre3 = ([AL(t-1)|0, it, AL(t)] @ W{2,3}[0:192] + b)*scale
// 16 timesteps per 64-thread block; 1024 blocks (128 batches x 8 chunks).
__global__ __launch_bounds__(64) void lpkt_pre2(
    const int* __restrict__ itseq, const float* __restrict__ E_it,
    const float* __restrict__ AL,
    const float* __restrict__ W2, const float* __restrict__ b2,
    const float* __restrict__ W3, const float* __restrict__ b3,
    float* __restrict__ pre2, float* __restrict__ pre3)
{
  __shared__ float sal[17][64];
  __shared__ float sit[16][64];
  const int d = threadIdx.x;
  const int b = blockIdx.x >> 3;
  const int t0 = (blockIdx.x & 7) * 16;
  #pragma unroll 4
  for (int i = 0; i < 17; ++i) {
    int tt = t0 - 1 + i;
    sal[i][d] = (tt >= 0) ? AL[(b*NS + tt)*ND + d] : 0.f;
  }
  #pragma unroll 4
  for (int i = 0; i < 16; ++i) {
    sit[i][d] = E_it[itseq[b*NS + t0 + i]*ND + d];
  }
  __syncthreads();
  float a2[16], a3[16];
  const float b2d = b2[d], b3d = b3[d];
  #pragma unroll
  for (int i = 0; i < 16; ++i) { a2[i] = b2d; a3[i] = b3d; }
  for (int k = 0; k < 64; ++k) {
    float w2v = W2[k*ND + d], w3v = W3[k*ND + d];
    #pragma unroll
    for (int i = 0; i < 16; ++i) {
      a2[i] = fmaf(sal[i][k], w2v, a2[i]);
      a3[i] = fmaf(sal[i][k], w3v, a3[i]);
    }
  }
  for (int k = 0; k < 64; ++k) {
    float w2v = W2[(64+k)*ND + d], w3v = W3[(64+k)*ND + d];
    #pragma unroll
    for (int i = 0; i < 16; ++i) {
      a2[i] = fmaf(sit[i][k], w2v, a2[i]);
      a3[i] = fmaf(sit[i][k], w3v, a3[i]);
    }
  }
  for (int k = 0; k < 64; ++k) {
    float w2v = W2[(128+k)*ND + d], w3v = W3[(128+k)*ND + d];
    #pragma unroll
    for (int i = 0; i < 16; ++i) {
      a2[i] = fmaf(sal[i+1][k], w2v, a2[i]);
      a3[i] = fmaf(sal[i+1][k], w3v, a3[i]);
    }
  }
  #pragma unroll
  for (int i = 0; i < 16; ++i) {
    int p = (b*NS + t0 + i)*ND + d;   // t=127 written but never consumed
    pre2[p] = a2[i]*(2.f*SC1);
    pre3[p] = a3[i]*SC1;
  }
}

#define LOADB() do {                                                         \
  _Pragma("unroll")                                                          \
  for (int t2_=0;t2_<2;++t2_)                                                \
    _Pragma("unroll")                                                        \
    for (int k0_=0;k0_<2;++k0_)                                              \
      bfr[t2_][k0_] = *(const short8*)&sh_hbf[bfofs[t2_][k0_]];              \
} while(0)

#define MFMA8() do {                                                         \
  _Pragma("unroll")                                                          \
  for (int t2_=0;t2_<2;++t2_){                                               \
    _Pragma("unroll")                                                        \
    for (int k0_=0;k0_<2;++k0_){                                             \
      acc[0][t2_] = __builtin_amdgcn_mfma_f32_16x16x32_bf16(aW[0][k0_], bfr[t2_][k0_], acc[0][t2_],0,0,0); \
      acc[1][t2_] = __builtin_amdgcn_mfma_f32_16x16x32_bf16(aW[1][k0_], bfr[t2_][k0_], acc[1][t2_],0,0,0); \
    }                                                                        \
  }                                                                          \
} while(0)

// acc init from pre4 (folds the gamma bias into the MFMA accumulator)
#define ACCINIT() do {                                                       \
  float4 p4a_ = *(const float4*)&sh_pre[slot][2][16*mm+4*g];                 \
  float4 p4b_ = *(const float4*)&sh_pre[slot][2][16*(mm+1)+4*g];             \
  f32x4 ia_ = (f32x4){p4a_.x,p4a_.y,p4a_.z,p4a_.w};                          \
  f32x4 ib_ = (f32x4){p4b_.x,p4b_.y,p4b_.z,p4b_.w};                          \
  acc[0][0]=ia_; acc[0][1]=ia_; acc[1][0]=ib_; acc[1][1]=ib_;                \
} while(0)

// ---------------- sequential recurrence
__global__ __launch_bounds__(512)
void lpkt_seq(
    const int* __restrict__ qseq, const float* __restrict__ qmat,
    const float* __restrict__ h0,
    const float* __restrict__ W2, const float* __restrict__ W3,
    const float* __restrict__ W4, const float* __restrict__ W5,
    const float* __restrict__ pre2, const float* __restrict__ pre3,
    const float* __restrict__ pre4, const float* __restrict__ pre5,
    float* __restrict__ out)
{
  __shared__ __align__(16) unsigned short sh_hbf[NC*ND];  // 16KB bf16 shadow
  __shared__ float sh_pre[32][4][64];                     // 32KB stream ring
  __shared__ float sh_qf[32][NC];                         // 16KB q-row ring
  __shared__ float sh_htp[4][64];
  __shared__ float sh_LG[64];
  __shared__ __align__(16) unsigned sh_LGb[32];           // LG packed bf16
  __shared__ float sh_out[NS];

  const int tid = threadIdx.x;
  const int w = tid>>6, l = tid&63;
  const int g = l>>4, li = l&15;
  const int b = blockIdx.x;
  const int Wq = w & 3, mm = (w>>2)*2;

  if (w==4) __builtin_amdgcn_s_setprio(1);

  // MFMA A-frags: W4a columns scaled by -log2e (all waves)
  short8 aW[2][2];
  #pragma unroll
  for (int mloc=0;mloc<2;++mloc)
    #pragma unroll
    for (int k0=0;k0<2;++k0){
      short8 v;
      #pragma unroll
      for (int j=0;j<8;++j){
        __hip_bfloat16 hb = __float2bfloat16(W4[(32*k0+8*g+j)*ND + 16*(mm+mloc)+li] * SC1);
        v[j] = *(short*)&hb;
      }
      aW[mloc][k0] = v;
    }
  // lgit A-frags: W4b columns scaled by -log2e (all waves)
  short8 aW4b[2][2];
  #pragma unroll
  for (int mloc=0;mloc<2;++mloc)
    #pragma unroll
    for (int k0=0;k0<2;++k0){
      short8 v;
      #pragma unroll
      for (int j=0;j<8;++j){
        __hip_bfloat16 hb = __float2bfloat16(W4[(64+32*k0+8*g+j)*ND + 16*(mm+mloc)+li] * SC1);
        v[j] = *(short*)&hb;
      }
      aW4b[mloc][k0] = v;
    }

  // chain weights, f16-packed: w4 only (a2/a3). w6: y weights.
  half2_t wA[32], wB[32];
  if (w==4){
    #pragma unroll
    for (int j=0;j<32;++j){
      wA[j] = pkrtz(W2[(192+2*j)*ND + l]*(2.f*SC1), W2[(193+2*j)*ND + l]*(2.f*SC1));
      wB[j] = pkrtz(W3[(192+2*j)*ND + l]*SC1,       W3[(193+2*j)*ND + l]*SC1);
    }
  } else if (w==6){
    #pragma unroll
    for (int j=0;j<32;++j)
      wA[j] = pkrtz(W5[(64+2*j)*ND + l]*SC1, W5[(65+2*j)*ND + l]*SC1);
  }

  // h init in regs + bf16 shadow
  float hreg[2][2][4];
  int wofs[2][2], bfofs[2][2];
  #pragma unroll
  for (int mloc=0;mloc<2;++mloc)
    #pragma unroll
    for (int t2=0;t2<2;++t2){
      int c  = 32*Wq + 16*t2 + li;
      int d0 = 16*(mm+mloc) + 4*g;
      wofs[t2][mloc] = HBF(c, d0);
      float4 v = *(const float4*)&h0[c*ND + d0];
      hreg[mloc][t2][0]=v.x; hreg[mloc][t2][1]=v.y;
      hreg[mloc][t2][2]=v.z; hreg[mloc][t2][3]=v.w;
      uint2 pk; pk.x = pk_bf16(v.x,v.y); pk.y = pk_bf16(v.z,v.w);
      *(uint2*)&sh_hbf[wofs[t2][mloc]] = pk;
    }
  #pragma unroll
  for (int t2=0;t2<2;++t2)
    #pragma unroll
    for (int k0=0;k0<2;++k0)
      bfofs[t2][k0] = HBF(32*Wq+16*t2+li, 32*k0+8*g);

  // qf ring init rows 0..16
  #pragma unroll
  for (int k2=0;k2<2;++k2){
    int f4id = tid + k2*512;
    if (f4id < 17*32){
      int r = f4id >> 5, c4 = (f4id & 31)*4;
      int qrow = qseq[b*NS + r];
      float4 v = *(const float4*)&qmat[qrow*NC + c4];
      *(float4*)&sh_qf[r][c4] = v;
    }
  }
  // pre ring init: steps 0..15
  #pragma unroll
  for (int k2=0;k2<2;++k2){
    int f4id = tid + k2*512;
    int u = f4id >> 6;
    int inner = f4id & 63;
    int s = inner >> 4, c4 = (inner & 15)*4;
    const float* ps = (s==0)?pre2:(s==1)?pre3:(s==2)?pre4:pre5;
    float4 v = *(const float4*)&ps[(size_t)(b*NS+u)*ND + c4];
    *(float4*)(&sh_pre[u][0][0] + inner*4) = v;
  }
  if (tid==0) sh_out[0] = 0.f;
  __syncthreads();

  // bootstrap htp: q(0).h0
  {
    float part[2][4] = {{0.f,0.f,0.f,0.f},{0.f,0.f,0.f,0.f}};
    #pragma unroll
    for (int t2=0;t2<2;++t2){
      float qv = sh_qf[0][32*Wq+16*t2+li];
      #pragma unroll
      for (int mloc=0;mloc<2;++mloc)
        #pragma unroll
        for (int r2=0;r2<4;++r2)
          part[mloc][r2] = fmaf(qv, hreg[mloc][t2][r2], part[mloc][r2]);
    }
    #pragma unroll
    for (int mloc=0;mloc<2;++mloc)
      #pragma unroll
      for (int r2=0;r2<4;++r2){ float v=part[mloc][r2]; DPP_ROWSUM(v); part[mloc][r2]=v; }
    if (li==15){
      #pragma unroll
      for (int mloc=0;mloc<2;++mloc){
        float4 pv; pv.x=part[mloc][0]; pv.y=part[mloc][1]; pv.z=part[mloc][2]; pv.w=part[mloc][3];
        *(float4*)&sh_htp[Wq][16*(mm+mloc)+4*g] = pv;
      }
    }
  }
  __syncthreads();

  float qc0 = sh_qf[0][32*Wq+li];
  float qc1 = sh_qf[0][32*Wq+16+li];

  const float* prebase;
  { int s = l>>4;
    const float* ps = (s==0)?pre2:(s==1)?pre3:(s==2)?pre4:pre5;
    prebase = ps + (size_t)(b*NS)*ND + (l&15)*4; }

  for (int t=0; t<127; ++t){
    const int slot = t & 31, sn = (t+1) & 31;

    // ================= Phase 1 =================
    f32x4 acc[2][2];
    short8 bfr[2][2];
    ACCINIT();

    if (w==4){
      // serial chain (w4 only): a2/a3 dual f16 dot -> LG -> sh_LG + sh_LGb
      float pv2 = sh_pre[slot][0][l], pv3 = sh_pre[slot][1][l];
      float htv = (sh_htp[0][l]+sh_htp[1][l])+(sh_htp[2][l]+sh_htp[3][l]);
      half2_t hpk = pkrtz(htv, dppswap(htv));
      float a20=pv2, a21=0.f, a30=pv3, a31=0.f;
      #pragma unroll
      for (int j=0;j<32;j+=2){
        half2_t ha = rlh2(hpk, 2*j), hb = rlh2(hpk, 2*j+2);
        a20 = dot2h(ha, wA[j],   a20); a21 = dot2h(hb, wA[j+1], a21);
        a30 = dot2h(ha, wB[j],   a30); a31 = dot2h(hb, wB[j+1], a31);
      }
      float LGl = gsig(a30+a31) * gsig(a20+a21);   // sigma(a3)*sigma(2*a2)
      sh_LG[l] = LGl;
      float nb = dppswap(LGl);
      if (!(l&1)) sh_LGb[l>>1] = pk_bf16(LGl, nb);
      LOADB(); MFMA8();
    } else if (w==6){
      if (t > 0){
        float pv5 = sh_pre[slot][3][l];
        float htv = (sh_htp[0][l]+sh_htp[1][l])+(sh_htp[2][l]+sh_htp[3][l]);
        half2_t hpk = pkrtz(htv, dppswap(htv));
        float z0 = pv5, z1 = 0.f;
        #pragma unroll
        for (int j=0;j<32;j+=2){
          z0 = dot2h(rlh2(hpk, 2*j),   wA[j],   z0);
          z1 = dot2h(rlh2(hpk, 2*j+2), wA[j+1], z1);
        }
        float yv = gsig(z0+z1);
        DPP_ROWSUM(yv);
        float s = (rl(yv,15)+rl(yv,31))+(rl(yv,47)+rl(yv,63));
        if (l==0) sh_out[t] = s*(1.f/64.f);
      }
      LOADB(); MFMA8();
    } else if (w==3){
      if ((t&15)==0){
        int t0r = t+17;
        #pragma unroll
        for (int rep=0; rep<8; ++rep){
          int f4id = rep*64 + l;
          int r = t0r + (f4id>>5);
          int c4 = (f4id & 31)*4;
          if (r < NS){
            int qrow = qseq[b*NS + r];
            float4 v = *(const float4*)&qmat[qrow*NC + c4];
            *(float4*)&sh_qf[r&31][c4] = v;
          }
        }
      }
      LOADB(); MFMA8();
    } else if (w==7){
      if ((t&15)==0){
        #pragma unroll
        for (int rep=0; rep<16; ++rep){
          int u = t+16+rep;
          if (u < NS){
            float4 v = *(const float4*)&prebase[(size_t)u*ND];
            *(float4*)(&sh_pre[u&31][0][0] + l*4) = v;
          }
        }
      }
      LOADB(); MFMA8();
    } else {
      LOADB(); MFMA8();
    }
    float qn0 = sh_qf[sn][32*Wq+li];
    float qn1 = sh_qf[sn][32*Wq+16+li];
    __syncthreads();

    // ================= Phase 2 =================
    {
      // lgit via 2 broadcast-B MFMAs (adds lgit[d] into acc; pre4 already in)
      short8 lgb[2];
      #pragma unroll
      for (int k0=0;k0<2;++k0)
        lgb[k0] = *(const short8*)((const char*)sh_LGb + 64*k0 + 16*g);
      #pragma unroll
      for (int mloc=0;mloc<2;++mloc)
        #pragma unroll
        for (int t2=0;t2<2;++t2){
          acc[mloc][t2] = __builtin_amdgcn_mfma_f32_16x16x32_bf16(aW4b[mloc][0], lgb[0], acc[mloc][t2],0,0,0);
          acc[mloc][t2] = __builtin_amdgcn_mfma_f32_16x16x32_bf16(aW4b[mloc][1], lgb[1], acc[mloc][t2],0,0,0);
        }

      float4 LG4[2];
      #pragma unroll
      for (int mloc=0;mloc<2;++mloc)
        LG4[mloc] = *(const float4*)&sh_LG[16*(mm+mloc)+4*g];

      float part[2][4] = {{0.f,0.f,0.f,0.f},{0.f,0.f,0.f,0.f}};
      #pragma unroll
      for (int t2=0;t2<2;++t2){
        float qcv = t2 ? qc1 : qc0;
        float qnv = t2 ? qn1 : qn0;
        #pragma unroll
        for (int mloc=0;mloc<2;++mloc){
          float lg4a[4] = {LG4[mloc].x, LG4[mloc].y, LG4[mloc].z, LG4[mloc].w};
          float hn[4];
          #pragma unroll
          for (int r2=0;r2<4;++r2){
            float gam = gsig(acc[mloc][t2][r2]);
            hn[r2] = fmaf(qcv, lg4a[r2], gam*hreg[mloc][t2][r2]);
            hreg[mloc][t2][r2] = hn[r2];
            part[mloc][r2] = fmaf(qnv, hn[r2], part[mloc][r2]);
          }
          uint2 pk; pk.x = pk_bf16(hn[0],hn[1]); pk.y = pk_bf16(hn[2],hn[3]);
          *(uint2*)&sh_hbf[wofs[t2][mloc]] = pk;
        }
      }
      #pragma unroll
      for (int mloc=0;mloc<2;++mloc)
        #pragma unroll
        for (int r2=0;r2<4;++r2){ float v=part[mloc][r2]; DPP_ROWSUM(v); part[mloc][r2]=v; }
      if (li==15){
        #pragma unroll
        for (int mloc=0;mloc<2;++mloc){
          float4 pv; pv.x=part[mloc][0]; pv.y=part[mloc][1]; pv.z=part[mloc][2]; pv.w=part[mloc][3];
          *(float4*)&sh_htp[Wq][16*(mm+mloc)+4*g] = pv;
        }
      }
      qc0 = qn0; qc1 = qn1;
    }
    __syncthreads();
  }

  // final output position 127 (sh_htp = q(127).h(127))
  if (w==6){
    float htv = (sh_htp[0][l]+sh_htp[1][l])+(sh_htp[2][l]+sh_htp[3][l]);
    half2_t hpk = pkrtz(htv, dppswap(htv));
    float z0 = sh_pre[31][3][l], z1 = 0.f;
    #pragma unroll
    for (int j=0;j<32;j+=2){
      z0 = dot2h(rlh2(hpk, 2*j),   wA[j],   z0);
      z1 = dot2h(rlh2(hpk, 2*j+2), wA[j+1], z1);
    }
    float yv = gsig(z0+z1);
    DPP_ROWSUM(yv);
    float s = (rl(yv,15)+rl(yv,31))+(rl(yv,47)+rl(yv,63));
    if (l==0) sh_out[127] = s*(1.f/64.f);
  }
  __syncthreads();
  if (tid < NS) out[b*NS + tid] = sh_out[tid];
}

extern "C" void kernel_launch(void* const* d_in, const int* in_sizes, int n_in,
                              void* d_out, int out_size, void* d_ws, size_t ws_size,
                              hipStream_t stream)
{
  const int*   qseq  = (const int*)d_in[0];
  const int*   cseq  = (const int*)d_in[1];
  const int*   itseq = (const int*)d_in[2];
  const int*   atseq = (const int*)d_in[3];
  const float* E_q   = (const float*)d_in[4];
  const float* E_c   = (const float*)d_in[5];
  const float* E_it  = (const float*)d_in[6];
  const float* E_at  = (const float*)d_in[7];
  const float* qmat  = (const float*)d_in[8];
  const float* h0    = (const float*)d_in[9];
  const float* W1    = (const float*)d_in[10];
  const float* b1    = (const float*)d_in[11];
  const float* W2    = (const float*)d_in[12];
  const float* b2    = (const float*)d_in[13];
  const float* W3    = (const float*)d_in[14];
  const float* b3    = (const float*)d_in[15];
  const float* W4    = (const float*)d_in[16];
  const float* b4    = (const float*)d_in[17];
  const float* W5    = (const float*)d_in[18];
  const float* b5    = (const float*)d_in[19];
  float* out = (float*)d_out;

  float* wsf  = (float*)d_ws;
  float* AL   = wsf;
  float* pre2 = wsf + 1*POS*ND;
  float* pre3 = wsf + 2*POS*ND;
  float* pre4 = wsf + 3*POS*ND;
  float* pre5 = wsf + 4*POS*ND;

  lpkt_pre1<<<1024, 64, 0, stream>>>(qseq, cseq, itseq, atseq,
                                     E_q, E_c, E_it, E_at,
                                     W1, b1, W4, b4, W5, b5,
                                     AL, pre4, pre5);
  lpkt_pre2<<<1024, 64, 0, stream>>>(itseq, E_it, AL, W2, b2, W3, b3, pre2, pre3);
  lpkt_seq<<<128, 512, 0, stream>>>(qseq, qmat, h0, W2, W3, W4, W5,
                                    pre2, pre3, pre4, pre5, out);
}

// Round 14
// 266.191 us; speedup vs baseline: 1.2579x; 1.2579x over previous
//
#include <hip/hip_runtime.h>
#include <hip/hip_bf16.h>

// LPKT forward. B=128, S=128, C=128, D=64.
//  - pre1/pre2: parallel precompute (4 positions/block, high occupancy),
//    outputs pre-scaled by -log2e (pre2 by -2log2e) for exp2 sigmoids.
//  - lpkt_seq: one 512-thread block per batch, 127-step recurrence, TWO
//    barriers per step. h in registers (8 waves x 32c x 32d), bf16 shadow in
//    LDS for MFMA (H4 = h @ W4a'). Serial chain (a2,a3,LG) on w4 only with
//    f16-packed register weights + v_dot2_f32_f16; lgit via 2 broadcast-B
//    MFMAs from sh_LGb. ALL bf16 packs via hardware v_cvt_pk_bf16_f32.
//    y head on w6; ring refills on w3 (q rows) / w7 (pre streams).

#define NB 128
#define NS 128
#define NC 128
#define ND 64
#define POS (NB*NS)

typedef __attribute__((ext_vector_type(8))) short short8;
typedef __attribute__((ext_vector_type(4))) float f32x4;
typedef __attribute__((ext_vector_type(2))) _Float16 half2_t;

__device__ __forceinline__ float rl(float v,int j){
  return __int_as_float(__builtin_amdgcn_readlane(__float_as_int(v), j));
}
__device__ __forceinline__ half2_t rlh2(half2_t v,int j){
  int x; __builtin_memcpy(&x,&v,4);
  x = __builtin_amdgcn_readlane(x,j);
  half2_t r; __builtin_memcpy(&r,&x,4); return r;
}
__device__ __forceinline__ half2_t pkrtz(float a, float b){
  auto t = __builtin_amdgcn_cvt_pkrtz(a,b);
  half2_t r; __builtin_memcpy(&r,&t,4); return r;
}
__device__ __forceinline__ unsigned pk_bf16(float lo, float hi){  // HW cvt_pk
  unsigned r;
  asm("v_cvt_pk_bf16_f32 %0, %1, %2" : "=v"(r) : "v"(lo), "v"(hi));
  return r;
}
__device__ __forceinline__ float dppswap(float v){  // lane 2k <-> 2k+1
  return __int_as_float(__builtin_amdgcn_update_dpp(0,__float_as_int(v),0xB1,0xF,0xF,true));
}
__device__ __forceinline__ float dot2h(half2_t a, half2_t b, float c){
#if __has_builtin(__builtin_amdgcn_fdot2)
  return __builtin_amdgcn_fdot2(a,b,c,false);
#else
  return fmaf((float)a[0],(float)b[0], fmaf((float)a[1],(float)b[1], c));
#endif
}

#define HBF(c, d) ((((c)<<6) + (d)) ^ (((c)&7)<<3))
#define DPP_ADD(v, CTRL) ((v) + __int_as_float(__builtin_amdgcn_update_dpp(0, __float_as_int(v), CTRL, 0xF, 0xF, true)))
#define DPP_ROWSUM(v) do { v = DPP_ADD(v,0x111); v = DPP_ADD(v,0x112); v = DPP_ADD(v,0x114); v = DPP_ADD(v,0x118); } while(0)

#define SC1 (-1.4426950408889634f)   /* -log2(e) */

__device__ __forceinline__ float gsig(float zp){   // sigmoid given pre-scaled arg
  return __builtin_amdgcn_rcpf(1.f + __builtin_amdgcn_exp2f(zp));
}

// ---------------- P1: AL = [e,at,c]@W1+b1 ; pre4=(it@W4c+b4)*SC1 ; pre5=(e@W5a+b5)*SC1
__global__ __launch_bounds__(64) void lpkt_pre1(
    const int* __restrict__ qseq, const int* __restrict__ cseq,
    const int* __restrict__ itseq, const int* __restrict__ atseq,
    const float* __restrict__ E_q, const float* __restrict__ E_c,
    const float* __restrict__ E_it, const float* __restrict__ E_at,
    const float* __restrict__ W1, const float* __restrict__ b1,
    const float* __restrict__ W4, const float* __restrict__ b4,
    const float* __restrict__ W5, const float* __restrict__ b5,
    float* __restrict__ AL, float* __restrict__ pre4, float* __restrict__ pre5)
{
  __shared__ float sx[4][192];
  __shared__ float sit[4][64];
  const int d = threadIdx.x;
  #pragma unroll
  for (int i = 0; i < 4; ++i) {
    int p = blockIdx.x + i*4096;
    sx[i][d]      = E_q[qseq[p]*ND + d];
    sx[i][64+d]   = E_at[atseq[p]*ND + d];
    sx[i][128+d]  = E_c[cseq[p]*ND + d];
    sit[i][d]     = E_it[itseq[p]*ND + d];
  }
  __syncthreads();
  float al[4], p4[4], p5[4];
  const float b1d = b1[d], b4d = b4[d], b5d = b5[d];
  #pragma unroll
  for (int i = 0; i < 4; ++i) { al[i] = b1d; p4[i] = b4d; p5[i] = b5d; }
  for (int k = 0; k < 192; ++k) {
    float wv = W1[k*ND + d];
    #pragma unroll
    for (int i = 0; i < 4; ++i) al[i] = fmaf(sx[i][k], wv, al[i]);
  }
  for (int k = 0; k < 64; ++k) {
    float wv4 = W4[(128+k)*ND + d];
    float wv5 = W5[k*ND + d];
    #pragma unroll
    for (int i = 0; i < 4; ++i) {
      p4[i] = fmaf(sit[i][k], wv4, p4[i]);
      p5[i] = fmaf(sx[i][k],  wv5, p5[i]);
    }
  }
  #pragma unroll
  for (int i = 0; i < 4; ++i) {
    int p = blockIdx.x + i*4096;
    AL[p*ND + d]   = al[i];
    pre4[p*ND + d] = p4[i]*SC1;
    pre5[p*ND + d] = p5[i]*SC1;
  }
}

// ---------------- P2: pre2/pre3 = ([AL(t-1)|0, it, AL(t)] @ W{2,3}[0:192] + b)*scale
__global__ __launch_bounds__(64) void lpkt_pre2(
    const int* __restrict__ itseq, const float* __restrict__ E_it,
    const float* __restrict__ AL,
    const float* __restrict__ W2, const float* __restrict__ b2,
    const float* __restrict__ W3, const float* __restrict__ b3,
    float* __restrict__ pre2, float* __restrict__ pre3)
{
  __shared__ float sx[4][192];
  const int d = threadIdx.x;
  int bs4[4];
  #pragma unroll
  for (int i = 0; i < 4; ++i) {
    int p = blockIdx.x + i*4064;
    int b = p / 127;
    int t = p - b*127;
    int bs = b*NS + t;
    bs4[i] = bs;
    sx[i][d]     = (t > 0) ? AL[(bs-1)*ND + d] : 0.f;
    sx[i][64+d]  = E_it[itseq[bs]*ND + d];
    sx[i][128+d] = AL[bs*ND + d];
  }
  __syncthreads();
  float a2[4], a3[4];
  const float b2d = b2[d], b3d = b3[d];
  #pragma unroll
  for (int i = 0; i < 4; ++i) { a2[i] = b2d; a3[i] = b3d; }
  for (int k = 0; k < 192; ++k) {
    float w2v = W2[k*ND + d];
    float w3v = W3[k*ND + d];
    #pragma unroll
    for (int i = 0; i < 4; ++i) {
      a2[i] = fmaf(sx[i][k], w2v, a2[i]);
      a3[i] = fmaf(sx[i][k], w3v, a3[i]);
    }
  }
  #pragma unroll
  for (int i = 0; i < 4; ++i) {
    pre2[bs4[i]*ND + d] = a2[i]*(2.f*SC1);
    pre3[bs4[i]*ND + d] = a3[i]*SC1;
  }
}

#define LOADB() do {                                                         \
  _Pragma("unroll")                                                          \
  for (int t2_=0;t2_<2;++t2_)                                                \
    _Pragma("unroll")                                                        \
    for (int k0_=0;k0_<2;++k0_)                                              \
      bfr[t2_][k0_] = *(const short8*)&sh_hbf[bfofs[t2_][k0_]];              \
} while(0)

#define MFMA8() do {                                                         \
  _Pragma("unroll")                                                          \
  for (int t2_=0;t2_<2;++t2_){                                               \
    _Pragma("unroll")                                                        \
    for (int k0_=0;k0_<2;++k0_){                                             \
      acc[0][t2_] = __builtin_amdgcn_mfma_f32_16x16x32_bf16(aW[0][k0_], bfr[t2_][k0_], acc[0][t2_],0,0,0); \
      acc[1][t2_] = __builtin_amdgcn_mfma_f32_16x16x32_bf16(aW[1][k0_], bfr[t2_][k0_], acc[1][t2_],0,0,0); \
    }                                                                        \
  }                                                                          \
} while(0)

// ---------------- sequential recurrence
__global__ __launch_bounds__(512)
void lpkt_seq(
    const int* __restrict__ qseq, const float* __restrict__ qmat,
    const float* __restrict__ h0,
    const float* __restrict__ W2, const float* __restrict__ W3,
    const float* __restrict__ W4, const float* __restrict__ W5,
    const float* __restrict__ pre2, const float* __restrict__ pre3,
    const float* __restrict__ pre4, const float* __restrict__ pre5,
    float* __restrict__ out)
{
  __shared__ __align__(16) unsigned short sh_hbf[NC*ND];  // 16KB bf16 shadow
  __shared__ float sh_pre[32][4][64];                     // 32KB stream ring
  __shared__ float sh_qf[32][NC];                         // 16KB q-row ring
  __shared__ float sh_htp[4][64];
  __shared__ float sh_LG[64];
  __shared__ __align__(16) unsigned sh_LGb[32];           // LG packed bf16
  __shared__ float sh_out[NS];

  const int tid = threadIdx.x;
  const int w = tid>>6, l = tid&63;
  const int g = l>>4, li = l&15;
  const int b = blockIdx.x;
  const int Wq = w & 3, mm = (w>>2)*2;

  if (w==4) __builtin_amdgcn_s_setprio(1);

  // MFMA A-frags: W4a columns scaled by -log2e (all waves)
  short8 aW[2][2];
  #pragma unroll
  for (int mloc=0;mloc<2;++mloc)
    #pragma unroll
    for (int k0=0;k0<2;++k0){
      short8 v;
      #pragma unroll
      for (int j=0;j<8;++j){
        __hip_bfloat16 hb = __float2bfloat16(W4[(32*k0+8*g+j)*ND + 16*(mm+mloc)+li] * SC1);
        v[j] = *(short*)&hb;
      }
      aW[mloc][k0] = v;
    }
  // lgit A-frags: W4b columns scaled by -log2e (all waves)
  short8 aW4b[2][2];
  #pragma unroll
  for (int mloc=0;mloc<2;++mloc)
    #pragma unroll
    for (int k0=0;k0<2;++k0){
      short8 v;
      #pragma unroll
      for (int j=0;j<8;++j){
        __hip_bfloat16 hb = __float2bfloat16(W4[(64+32*k0+8*g+j)*ND + 16*(mm+mloc)+li] * SC1);
        v[j] = *(short*)&hb;
      }
      aW4b[mloc][k0] = v;
    }

  // chain weights, f16-packed: w4 only (a2/a3). w6: y weights.
  half2_t wA[32], wB[32];
  if (w==4){
    #pragma unroll
    for (int j=0;j<32;++j){
      wA[j] = pkrtz(W2[(192+2*j)*ND + l]*(2.f*SC1), W2[(193+2*j)*ND + l]*(2.f*SC1));
      wB[j] = pkrtz(W3[(192+2*j)*ND + l]*SC1,       W3[(193+2*j)*ND + l]*SC1);
    }
  } else if (w==6){
    #pragma unroll
    for (int j=0;j<32;++j)
      wA[j] = pkrtz(W5[(64+2*j)*ND + l]*SC1, W5[(65+2*j)*ND + l]*SC1);
  }

  // h init in regs + bf16 shadow
  float hreg[2][2][4];
  int wofs[2][2], bfofs[2][2];
  #pragma unroll
  for (int mloc=0;mloc<2;++mloc)
    #pragma unroll
    for (int t2=0;t2<2;++t2){
      int c  = 32*Wq + 16*t2 + li;
      int d0 = 16*(mm+mloc) + 4*g;
      wofs[t2][mloc] = HBF(c, d0);
      float4 v = *(const float4*)&h0[c*ND + d0];
      hreg[mloc][t2][0]=v.x; hreg[mloc][t2][1]=v.y;
      hreg[mloc][t2][2]=v.z; hreg[mloc][t2][3]=v.w;
      uint2 pk; pk.x = pk_bf16(v.x,v.y); pk.y = pk_bf16(v.z,v.w);
      *(uint2*)&sh_hbf[wofs[t2][mloc]] = pk;
    }
  #pragma unroll
  for (int t2=0;t2<2;++t2)
    #pragma unroll
    for (int k0=0;k0<2;++k0)
      bfofs[t2][k0] = HBF(32*Wq+16*t2+li, 32*k0+8*g);

  // qf ring init rows 0..16
  #pragma unroll
  for (int k2=0;k2<2;++k2){
    int f4id = tid + k2*512;
    if (f4id < 17*32){
      int r = f4id >> 5, c4 = (f4id & 31)*4;
      int qrow = qseq[b*NS + r];
      float4 v = *(const float4*)&qmat[qrow*NC + c4];
      *(float4*)&sh_qf[r][c4] = v;
    }
  }
  // pre ring init: steps 0..15
  #pragma unroll
  for (int k2=0;k2<2;++k2){
    int f4id = tid + k2*512;
    int u = f4id >> 6;
    int inner = f4id & 63;
    int s = inner >> 4, c4 = (inner & 15)*4;
    const float* ps = (s==0)?pre2:(s==1)?pre3:(s==2)?pre4:pre5;
    float4 v = *(const float4*)&ps[(size_t)(b*NS+u)*ND + c4];
    *(float4*)(&sh_pre[u][0][0] + inner*4) = v;
  }
  if (tid==0) sh_out[0] = 0.f;
  __syncthreads();

  // bootstrap htp: q(0).h0
  {
    float part[2][4] = {{0.f,0.f,0.f,0.f},{0.f,0.f,0.f,0.f}};
    #pragma unroll
    for (int t2=0;t2<2;++t2){
      float qv = sh_qf[0][32*Wq+16*t2+li];
      #pragma unroll
      for (int mloc=0;mloc<2;++mloc)
        #pragma unroll
        for (int r2=0;r2<4;++r2)
          part[mloc][r2] = fmaf(qv, hreg[mloc][t2][r2], part[mloc][r2]);
    }
    #pragma unroll
    for (int mloc=0;mloc<2;++mloc)
      #pragma unroll
      for (int r2=0;r2<4;++r2){ float v=part[mloc][r2]; DPP_ROWSUM(v); part[mloc][r2]=v; }
    if (li==15){
      #pragma unroll
      for (int mloc=0;mloc<2;++mloc){
        float4 pv; pv.x=part[mloc][0]; pv.y=part[mloc][1]; pv.z=part[mloc][2]; pv.w=part[mloc][3];
        *(float4*)&sh_htp[Wq][16*(mm+mloc)+4*g] = pv;
      }
    }
  }
  __syncthreads();

  float qc0 = sh_qf[0][32*Wq+li];
  float qc1 = sh_qf[0][32*Wq+16+li];

  const float* prebase;
  { int s = l>>4;
    const float* ps = (s==0)?pre2:(s==1)?pre3:(s==2)?pre4:pre5;
    prebase = ps + (size_t)(b*NS)*ND + (l&15)*4; }

  for (int t=0; t<127; ++t){
    const int slot = t & 31, sn = (t+1) & 31;

    // ================= Phase 1 =================
    f32x4 acc[2][2];
    #pragma unroll
    for (int mloc=0;mloc<2;++mloc)
      #pragma unroll
      for (int t2=0;t2<2;++t2)
        acc[mloc][t2] = (f32x4){0.f,0.f,0.f,0.f};
    short8 bfr[2][2];

    if (w==4){
      // serial chain (w4 only): a2/a3 dual f16 dot -> LG -> sh_LG + sh_LGb
      float pv2 = sh_pre[slot][0][l], pv3 = sh_pre[slot][1][l];
      float htv = (sh_htp[0][l]+sh_htp[1][l])+(sh_htp[2][l]+sh_htp[3][l]);
      half2_t hpk = pkrtz(htv, dppswap(htv));
      float a20=pv2, a21=0.f, a30=pv3, a31=0.f;
      #pragma unroll
      for (int j=0;j<32;j+=2){
        half2_t ha = rlh2(hpk, 2*j), hb = rlh2(hpk, 2*j+2);
        a20 = dot2h(ha, wA[j],   a20); a21 = dot2h(hb, wA[j+1], a21);
        a30 = dot2h(ha, wB[j],   a30); a31 = dot2h(hb, wB[j+1], a31);
      }
      float LGl = gsig(a30+a31) * gsig(a20+a21);   // sigma(a3)*sigma(2*a2)
      sh_LG[l] = LGl;
      float nb = dppswap(LGl);
      if (!(l&1)) sh_LGb[l>>1] = pk_bf16(LGl, nb);
      LOADB(); MFMA8();
    } else if (w==6){
      if (t > 0){
        float pv5 = sh_pre[slot][3][l];
        float htv = (sh_htp[0][l]+sh_htp[1][l])+(sh_htp[2][l]+sh_htp[3][l]);
        half2_t hpk = pkrtz(htv, dppswap(htv));
        float z0 = pv5, z1 = 0.f;
        #pragma unroll
        for (int j=0;j<32;j+=2){
          z0 = dot2h(rlh2(hpk, 2*j),   wA[j],   z0);
          z1 = dot2h(rlh2(hpk, 2*j+2), wA[j+1], z1);
        }
        float yv = gsig(z0+z1);
        DPP_ROWSUM(yv);
        float s = (rl(yv,15)+rl(yv,31))+(rl(yv,47)+rl(yv,63));
        if (l==0) sh_out[t] = s*(1.f/64.f);
      }
      LOADB(); MFMA8();
    } else if (w==3){
      if ((t&15)==0){
        int t0r = t+17;
        #pragma unroll
        for (int rep=0; rep<8; ++rep){
          int f4id = rep*64 + l;
          int r = t0r + (f4id>>5);
          int c4 = (f4id & 31)*4;
          if (r < NS){
            int qrow = qseq[b*NS + r];
            float4 v = *(const float4*)&qmat[qrow*NC + c4];
            *(float4*)&sh_qf[r&31][c4] = v;
          }
        }
      }
      LOADB(); MFMA8();
    } else if (w==7){
      if ((t&15)==0){
        #pragma unroll
        for (int rep=0; rep<16; ++rep){
          int u = t+16+rep;
          if (u < NS){
            float4 v = *(const float4*)&prebase[(size_t)u*ND];
            *(float4*)(&sh_pre[u&31][0][0] + l*4) = v;
          }
        }
      }
      LOADB(); MFMA8();
    } else {
      LOADB(); MFMA8();
    }
    float qn0 = sh_qf[sn][32*Wq+li];
    float qn1 = sh_qf[sn][32*Wq+16+li];
    __syncthreads();

    // ================= Phase 2 =================
    {
      // lgit via 2 broadcast-B MFMAs (adds lgit[d] to every row of acc)
      short8 lgb[2];
      #pragma unroll
      for (int k0=0;k0<2;++k0)
        lgb[k0] = *(const short8*)((const char*)sh_LGb + 64*k0 + 16*g);
      #pragma unroll
      for (int mloc=0;mloc<2;++mloc)
        #pragma unroll
        for (int t2=0;t2<2;++t2){
          acc[mloc][t2] = __builtin_amdgcn_mfma_f32_16x16x32_bf16(aW4b[mloc][0], lgb[0], acc[mloc][t2],0,0,0);
          acc[mloc][t2] = __builtin_amdgcn_mfma_f32_16x16x32_bf16(aW4b[mloc][1], lgb[1], acc[mloc][t2],0,0,0);
        }

      float4 LG4[2]; float gi[2][4];
      #pragma unroll
      for (int mloc=0;mloc<2;++mloc){
        int d0 = 16*(mm+mloc)+4*g;
        LG4[mloc] = *(const float4*)&sh_LG[d0];
        float4 p4v = *(const float4*)&sh_pre[slot][2][d0];   // pre4 (scaled)
        gi[mloc][0]=p4v.x; gi[mloc][1]=p4v.y; gi[mloc][2]=p4v.z; gi[mloc][3]=p4v.w;
      }
      float part[2][4] = {{0.f,0.f,0.f,0.f},{0.f,0.f,0.f,0.f}};
      #pragma unroll
      for (int t2=0;t2<2;++t2){
        float qcv = t2 ? qc1 : qc0;
        float qnv = t2 ? qn1 : qn0;
        #pragma unroll
        for (int mloc=0;mloc<2;++mloc){
          float lg4a[4] = {LG4[mloc].x, LG4[mloc].y, LG4[mloc].z, LG4[mloc].w};
          float hn[4];
          #pragma unroll
          for (int r2=0;r2<4;++r2){
            float gam = gsig(acc[mloc][t2][r2] + gi[mloc][r2]);
            hn[r2] = fmaf(qcv, lg4a[r2], gam*hreg[mloc][t2][r2]);
            hreg[mloc][t2][r2] = hn[r2];
            part[mloc][r2] = fmaf(qnv, hn[r2], part[mloc][r2]);
          }
          uint2 pk; pk.x = pk_bf16(hn[0],hn[1]); pk.y = pk_bf16(hn[2],hn[3]);
          *(uint2*)&sh_hbf[wofs[t2][mloc]] = pk;
        }
      }
      #pragma unroll
      for (int mloc=0;mloc<2;++mloc)
        #pragma unroll
        for (int r2=0;r2<4;++r2){ float v=part[mloc][r2]; DPP_ROWSUM(v); part[mloc][r2]=v; }
      if (li==15){
        #pragma unroll
        for (int mloc=0;mloc<2;++mloc){
          float4 pv; pv.x=part[mloc][0]; pv.y=part[mloc][1]; pv.z=part[mloc][2]; pv.w=part[mloc][3];
          *(float4*)&sh_htp[Wq][16*(mm+mloc)+4*g] = pv;
        }
      }
      qc0 = qn0; qc1 = qn1;
    }
    __syncthreads();
  }

  // final output position 127 (sh_htp = q(127).h(127))
  if (w==6){
    float htv = (sh_htp[0][l]+sh_htp[1][l])+(sh_htp[2][l]+sh_htp[3][l]);
    half2_t hpk = pkrtz(htv, dppswap(htv));
    float z0 = sh_pre[31][3][l], z1 = 0.f;
    #pragma unroll
    for (int j=0;j<32;j+=2){
      z0 = dot2h(rlh2(hpk, 2*j),   wA[j],   z0);
      z1 = dot2h(rlh2(hpk, 2*j+2), wA[j+1], z1);
    }
    float yv = gsig(z0+z1);
    DPP_ROWSUM(yv);
    float s = (rl(yv,15)+rl(yv,31))+(rl(yv,47)+rl(yv,63));
    if (l==0) sh_out[127] = s*(1.f/64.f);
  }
  __syncthreads();
  if (tid < NS) out[b*NS + tid] = sh_out[tid];
}

extern "C" void kernel_launch(void* const* d_in, const int* in_sizes, int n_in,
                              void* d_out, int out_size, void* d_ws, size_t ws_size,
                              hipStream_t stream)
{
  const int*   qseq  = (const int*)d_in[0];
  const int*   cseq  = (const int*)d_in[1];
  const int*   itseq = (const int*)d_in[2];
  const int*   atseq = (const int*)d_in[3];
  const float* E_q   = (const float*)d_in[4];
  const float* E_c   = (const float*)d_in[5];
  const float* E_it  = (const float*)d_in[6];
  const float* E_at  = (const float*)d_in[7];
  const float* qmat  = (const float*)d_in[8];
  const float* h0    = (const float*)d_in[9];
  const float* W1    = (const float*)d_in[10];
  const float* b1    = (const float*)d_in[11];
  const float* W2    = (const float*)d_in[12];
  const float* b2    = (const float*)d_in[13];
  const float* W3    = (const float*)d_in[14];
  const float* b3    = (const float*)d_in[15];
  const float* W4    = (const float*)d_in[16];
  const float* b4    = (const float*)d_in[17];
  const float* W5    = (const float*)d_in[18];
  const float* b5    = (const float*)d_in[19];
  float* out = (float*)d_out;

  float* wsf  = (float*)d_ws;
  float* AL   = wsf;
  float* pre2 = wsf + 1*POS*ND;
  float* pre3 = wsf + 2*POS*ND;
  float* pre4 = wsf + 3*POS*ND;
  float* pre5 = wsf + 4*POS*ND;

  lpkt_pre1<<<4096, 64, 0, stream>>>(qseq, cseq, itseq, atseq,
                                     E_q, E_c, E_it, E_at,
                                     W1, b1, W4, b4, W5, b5,
                                     AL, pre4, pre5);
  lpkt_pre2<<<4064, 64, 0, stream>>>(itseq, E_it, AL, W2, b2, W3, b3, pre2, pre3);
  lpkt_seq<<<128, 512, 0, stream>>>(qseq, qmat, h0, W2, W3, W4, W5,
                                    pre2, pre3, pre4, pre5, out);
}